// Round 1
// baseline (1236.507 us; speedup 1.0000x reference)
//
#include <hip/hip_runtime.h>
#include <math.h>

#define EDIM 1024
#define NH   16
#define HD   64
#define BATCH 2
#define SEQ  2048
#define NROW (BATCH*SEQ)   // 4096
#define YAT_EPS 0.1f

// ---------------------------------------------------------------------------
// GEMM: C = A[4096,1024] @ W[1024,1024] + bias[1024]
// head_store==1: scatter to head-major [B,H,S,D]; else plain [M,N].
// 64x64 tile, BK=16, 256 threads, 4x4 accum/thread, fp32 vector ALU.
// ---------------------------------------------------------------------------
__global__ __launch_bounds__(256)
void gemm_kernel(const float* __restrict__ A, const float* __restrict__ W,
                 const float* __restrict__ bias, float* __restrict__ C,
                 int head_store)
{
    __shared__ float As2[16][68];  // [k][m] transposed A tile (scalar writes conflict-free)
    __shared__ float Ws [16][72];  // [k][n]

    const int tid = threadIdx.x;
    const int tx = tid & 15;       // n-quad
    const int ty = tid >> 4;       // m-quad
    const int bm = blockIdx.x * 64;
    const int bn = blockIdx.y * 64;

    const int am  = tid >> 2;            // 0..63
    const int ak4 = (tid & 3) << 2;      // 0,4,8,12
    const int wk  = tid >> 4;            // 0..15
    const int wn4 = (tid & 15) << 2;     // 0..60

    float acc[4][4] = {{0.f}};

    for (int k0 = 0; k0 < 1024; k0 += 16) {
        const float4 av = *(const float4*)(A + (size_t)(bm + am) * 1024 + k0 + ak4);
        const float4 wv = *(const float4*)(W + (size_t)(k0 + wk) * 1024 + bn + wn4);
        __syncthreads();
        As2[ak4 + 0][am] = av.x;
        As2[ak4 + 1][am] = av.y;
        As2[ak4 + 2][am] = av.z;
        As2[ak4 + 3][am] = av.w;
        *(float4*)(&Ws[wk][wn4]) = wv;
        __syncthreads();
#pragma unroll
        for (int kk = 0; kk < 16; ++kk) {
            const float4 a4 = *(const float4*)(&As2[kk][ty << 2]);
            const float4 w4 = *(const float4*)(&Ws[kk][tx << 2]);
            const float aa[4] = {a4.x, a4.y, a4.z, a4.w};
            const float ww[4] = {w4.x, w4.y, w4.z, w4.w};
#pragma unroll
            for (int i = 0; i < 4; ++i)
#pragma unroll
                for (int j = 0; j < 4; ++j)
                    acc[i][j] += aa[i] * ww[j];
        }
    }

    const float4 bv = *(const float4*)(bias + bn + (tx << 2));
    const float bb[4] = {bv.x, bv.y, bv.z, bv.w};
#pragma unroll
    for (int i = 0; i < 4; ++i) {
        const int row = bm + (ty << 2) + i;
        const int col = bn + (tx << 2);
        float4 o;
        o.x = acc[i][0] + bb[0];
        o.y = acc[i][1] + bb[1];
        o.z = acc[i][2] + bb[2];
        o.w = acc[i][3] + bb[3];
        if (head_store) {
            const int b = row >> 11;          // / SEQ
            const int s = row & (SEQ - 1);
            const int h = col >> 6;
            const int d = col & 63;
            *(float4*)(C + ((size_t)((b * NH + h) * SEQ + s)) * HD + d) = o;
        } else {
            *(float4*)(C + (size_t)row * EDIM + col) = o;
        }
    }
}

// ---------------------------------------------------------------------------
// L2-normalize rows of 64 (one wave per row), in place, for Q and K.
// ---------------------------------------------------------------------------
__global__ __launch_bounds__(256)
void l2norm_kernel(float* __restrict__ Q, float* __restrict__ K)
{
    const int lane = threadIdx.x & 63;
    const int w    = threadIdx.x >> 6;
    const size_t row = (size_t)blockIdx.x * 4 + w;
    float* p = blockIdx.y ? K : Q;
    const size_t idx = row * HD + lane;
    const float v = p[idx];
    float ss = v * v;
#pragma unroll
    for (int m = 32; m > 0; m >>= 1) ss += __shfl_xor(ss, m);
    p[idx] = v / (sqrtf(ss) + 1e-8f);
}

// ---------------------------------------------------------------------------
// Yat attention, streaming (flash-style, no softmax max needed: scores > 0).
// One block = 64 queries of one (b,h); sweep all 2048 keys in 64-tiles.
// LDS: Qst [d][q] 16KB + KV (K:[d][k] then V:[k][d]) 16KB + Ps [q][65] 16.6KB.
// ---------------------------------------------------------------------------
__global__ __launch_bounds__(256)
void yat_attn_kernel(const float* __restrict__ Qn, const float* __restrict__ Kn,
                     const float* __restrict__ V,  float* __restrict__ Aout)
{
    __shared__ float Qst[64 * 64];   // [d][q]
    __shared__ float KV [64 * 64];   // phase K: [d][k]; phase V: [k][d]
    __shared__ float Ps [64 * 65];   // [q][k] pad->65 (addr = q+kk mod 32, conflict-free reads)

    const int tid = threadIdx.x;
    const int tx = tid & 15;
    const int ty = tid >> 4;
    const int q0 = blockIdx.x << 6;
    const int bh = blockIdx.y;

    const float* Qb = Qn + (size_t)bh * SEQ * HD;
    const float* Kb = Kn + (size_t)bh * SEQ * HD;
    const float* Vb = V  + (size_t)bh * SEQ * HD;

    // stage Q tile transposed: Qst[d][q]
#pragma unroll
    for (int it = 0; it < 4; ++it) {
        const int f  = tid + it * 256;      // float4 index 0..1023
        const int q  = f >> 4;              // 0..63
        const int d4 = (f & 15) << 2;       // 0..60
        const float4 v4 = *(const float4*)(Qb + (size_t)(q0 + q) * HD + d4);
        Qst[(d4 + 0) * 64 + q] = v4.x;
        Qst[(d4 + 1) * 64 + q] = v4.y;
        Qst[(d4 + 2) * 64 + q] = v4.z;
        Qst[(d4 + 3) * 64 + q] = v4.w;
    }

    float O[4][4] = {{0.f}};
    float rs[4]   = {0.f, 0.f, 0.f, 0.f};

    for (int t0 = 0; t0 < SEQ; t0 += 64) {
        // prefetch K and V tiles into registers (coalesced float4)
        float4 kreg[4], vreg[4];
#pragma unroll
        for (int it = 0; it < 4; ++it) {
            const int f  = tid + it * 256;
            const int r  = f >> 4;
            const int d4 = (f & 15) << 2;
            kreg[it] = *(const float4*)(Kb + (size_t)(t0 + r) * HD + d4);
            vreg[it] = *(const float4*)(Vb + (size_t)(t0 + r) * HD + d4);
        }
        __syncthreads();                     // [A] prev PV done with KV and Ps
        // K tile transposed into KV[d][k]
#pragma unroll
        for (int it = 0; it < 4; ++it) {
            const int f  = tid + it * 256;
            const int r  = f >> 4;
            const int d4 = (f & 15) << 2;
            KV[(d4 + 0) * 64 + r] = kreg[it].x;
            KV[(d4 + 1) * 64 + r] = kreg[it].y;
            KV[(d4 + 2) * 64 + r] = kreg[it].z;
            KV[(d4 + 3) * 64 + r] = kreg[it].w;
        }
        __syncthreads();                     // [B] K staged

        // S[q][k] = sum_d Qst[d][q] * KV[d][k]
        float acc[4][4] = {{0.f}};
#pragma unroll 8
        for (int d = 0; d < 64; ++d) {
            const float4 a4 = *(const float4*)(&Qst[d * 64 + (ty << 2)]);
            const float4 b4 = *(const float4*)(&KV [d * 64 + (tx << 2)]);
            const float aa[4] = {a4.x, a4.y, a4.z, a4.w};
            const float bb[4] = {b4.x, b4.y, b4.z, b4.w};
#pragma unroll
            for (int i = 0; i < 4; ++i)
#pragma unroll
                for (int j = 0; j < 4; ++j)
                    acc[i][j] += aa[i] * bb[j];
        }

        // yat score + row-sum accumulation, write P to LDS
#pragma unroll
        for (int i = 0; i < 4; ++i) {
#pragma unroll
            for (int j = 0; j < 4; ++j) {
                const float dot = acc[i][j];
                const float on  = 1.0f + dot;
                const float p   = (on * on) / (YAT_EPS + (1.0f - dot));
                rs[i] += p;
                Ps[((ty << 2) + i) * 65 + (tx << 2) + j] = p;
            }
        }
        __syncthreads();                     // [C] S-GEMM reads done; Ps visible
        // V tile into KV[k][d]
#pragma unroll
        for (int it = 0; it < 4; ++it) {
            const int f  = tid + it * 256;
            const int r  = f >> 4;
            const int d4 = (f & 15) << 2;
            *(float4*)(&KV[r * 64 + d4]) = vreg[it];
        }
        __syncthreads();                     // [D] V staged

        // O[q][d] += P[q][k] * V[k][d]
#pragma unroll 4
        for (int kk = 0; kk < 64; ++kk) {
            const float4 v4 = *(const float4*)(&KV[kk * 64 + (tx << 2)]);
            const float vv[4] = {v4.x, v4.y, v4.z, v4.w};
            const float a0 = Ps[((ty << 2) + 0) * 65 + kk];
            const float a1 = Ps[((ty << 2) + 1) * 65 + kk];
            const float a2 = Ps[((ty << 2) + 2) * 65 + kk];
            const float a3 = Ps[((ty << 2) + 3) * 65 + kk];
            O[0][0] += a0 * vv[0]; O[0][1] += a0 * vv[1]; O[0][2] += a0 * vv[2]; O[0][3] += a0 * vv[3];
            O[1][0] += a1 * vv[0]; O[1][1] += a1 * vv[1]; O[1][2] += a1 * vv[2]; O[1][3] += a1 * vv[3];
            O[2][0] += a2 * vv[0]; O[2][1] += a2 * vv[1]; O[2][2] += a2 * vv[2]; O[2][3] += a2 * vv[3];
            O[3][0] += a3 * vv[0]; O[3][1] += a3 * vv[1]; O[3][2] += a3 * vv[2]; O[3][3] += a3 * vv[3];
        }
    }

    // reduce row sums across the 16 lanes sharing ty (consecutive lanes in wave)
    const int b = bh >> 4;
    const int h = bh & 15;
#pragma unroll
    for (int i = 0; i < 4; ++i) {
        float t = rs[i];
        t += __shfl_xor(t, 1);
        t += __shfl_xor(t, 2);
        t += __shfl_xor(t, 4);
        t += __shfl_xor(t, 8);
        const float inv = 1.0f / (t + 1e-6f);
        const int s = q0 + (ty << 2) + i;
        float4 o;
        o.x = O[i][0] * inv; o.y = O[i][1] * inv; o.z = O[i][2] * inv; o.w = O[i][3] * inv;
        *(float4*)(Aout + ((size_t)(b * SEQ + s)) * EDIM + (h << 6) + (tx << 2)) = o;
    }
}

// ---------------------------------------------------------------------------
extern "C" void kernel_launch(void* const* d_in, const int* in_sizes, int n_in,
                              void* d_out, int out_size, void* d_ws, size_t ws_size,
                              hipStream_t stream)
{
    const float* x  = (const float*)d_in[0];
    const float* Wq = (const float*)d_in[1];
    const float* bq = (const float*)d_in[2];
    const float* Wk = (const float*)d_in[3];
    const float* bk = (const float*)d_in[4];
    const float* Wv = (const float*)d_in[5];
    const float* bv = (const float*)d_in[6];
    const float* Wo = (const float*)d_in[7];
    const float* bo = (const float*)d_in[8];
    float* out = (float*)d_out;

    // workspace layout (fp32): Q | K | V (head-major [B,H,S,D]) | attn out [B,S,E]
    float* ws = (float*)d_ws;
    const size_t T = (size_t)NROW * EDIM;   // 4M elements = 16 MB each
    float* Q  = ws;
    float* K  = ws + T;
    float* Vv = ws + 2 * T;
    float* AO = ws + 3 * T;

    const dim3 gb(NROW / 64, EDIM / 64);    // (64, 16)
    gemm_kernel<<<gb, 256, 0, stream>>>(x, Wq, bq, Q, 1);
    gemm_kernel<<<gb, 256, 0, stream>>>(x, Wk, bk, K, 1);
    gemm_kernel<<<gb, 256, 0, stream>>>(x, Wv, bv, Vv, 1);
    l2norm_kernel<<<dim3(BATCH * NH * SEQ / 4, 2), 256, 0, stream>>>(Q, K);
    yat_attn_kernel<<<dim3(SEQ / 64, BATCH * NH), 256, 0, stream>>>(Q, K, Vv, AO);
    gemm_kernel<<<gb, 256, 0, stream>>>(AO, Wo, bo, out, 0);
}

// Round 2
// 285.061 us; speedup vs baseline: 4.3377x; 4.3377x over previous
//
#include <hip/hip_runtime.h>
#include <math.h>

#define EDIM 1024
#define NH   16
#define HD   64
#define BATCH 2
#define SEQ  2048
#define NROW (BATCH*SEQ)   // 4096
#define YAT_EPS 0.1f

typedef _Float16 f16;
typedef _Float16 f16x8 __attribute__((ext_vector_type(8)));
typedef _Float16 f16x4 __attribute__((ext_vector_type(4)));
typedef float    f32x4 __attribute__((ext_vector_type(4)));

// ---------------------------------------------------------------------------
// fp32 -> f16 elementwise cast (x). 4 elems/thread.
// ---------------------------------------------------------------------------
__global__ __launch_bounds__(256)
void cast_f16_kernel(const float* __restrict__ src, f16* __restrict__ dst)
{
    const int i = (blockIdx.x * 256 + threadIdx.x) * 4;
    const float4 v = *(const float4*)(src + i);
    f16x4 o = {(f16)v.x, (f16)v.y, (f16)v.z, (f16)v.w};
    *(f16x4*)(dst + i) = o;
}

// ---------------------------------------------------------------------------
// W [1024 k][1024 n] fp32  ->  Wt [1024 n][1024 k] f16  (32x32 LDS transpose)
// ---------------------------------------------------------------------------
__global__ __launch_bounds__(256)
void transcast_kernel(const float* __restrict__ W, f16* __restrict__ Wt)
{
    __shared__ float T[32][33];
    const int t = threadIdx.x;
    const int r = t >> 3, c4 = (t & 7) * 4;
    const int bi = blockIdx.x * 32, bj = blockIdx.y * 32;
    const float4 v = *(const float4*)(W + (size_t)(bi + r) * 1024 + bj + c4);
    T[r][c4 + 0] = v.x; T[r][c4 + 1] = v.y; T[r][c4 + 2] = v.z; T[r][c4 + 3] = v.w;
    __syncthreads();
    f16x4 o = {(f16)T[c4 + 0][r], (f16)T[c4 + 1][r], (f16)T[c4 + 2][r], (f16)T[c4 + 3][r]};
    *(f16x4*)(Wt + (size_t)(bj + r) * 1024 + bi + c4) = o;
}

// ---------------------------------------------------------------------------
// MFMA GEMM: C = A[4096,1024] @ Wt[n][k]^T + bias.
// 128x128 tile, BK=64, 4 waves (2x2 quadrants), 4x4 16x16x32 frags per wave.
// epi: 0 = fp32 out [M,N]; 1 = l2norm rows-of-64 -> f16 [b,h,s,d];
//      2 = f16 transposed [b,h,d,s] (for V).
// ---------------------------------------------------------------------------
__global__ __launch_bounds__(256)
void gemm_f16(const f16* __restrict__ A, const f16* __restrict__ Bt,
              const float* __restrict__ bias, void* __restrict__ Cout, int epi)
{
    __shared__ f16 As[128 * 72];   // row stride 72 f16 (144B, 16B-aligned, 2-way banks)
    __shared__ f16 Bs[128 * 72];

    const int tid  = threadIdx.x;
    const int lane = tid & 63;
    const int w    = tid >> 6;
    const int cl   = lane & 15;
    const int quad = lane >> 4;
    const int wm = w & 1, wn = w >> 1;
    const int bm = blockIdx.x * 128, bn = blockIdx.y * 128;

    const int sr = tid >> 3, sc = tid & 7;   // staging: 8 chunks of 8 f16 per row

    f32x4 acc[4][4];
#pragma unroll
    for (int i = 0; i < 4; ++i)
#pragma unroll
        for (int j = 0; j < 4; ++j) acc[i][j] = (f32x4){0.f, 0.f, 0.f, 0.f};

    for (int k0 = 0; k0 < 1024; k0 += 64) {
        f16x8 av[4], bv[4];
#pragma unroll
        for (int i = 0; i < 4; ++i) {
            av[i] = *(const f16x8*)(A  + (size_t)(bm + sr + i * 32) * 1024 + k0 + sc * 8);
            bv[i] = *(const f16x8*)(Bt + (size_t)(bn + sr + i * 32) * 1024 + k0 + sc * 8);
        }
        __syncthreads();
#pragma unroll
        for (int i = 0; i < 4; ++i) {
            *(f16x8*)(&As[(sr + i * 32) * 72 + sc * 8]) = av[i];
            *(f16x8*)(&Bs[(sr + i * 32) * 72 + sc * 8]) = bv[i];
        }
        __syncthreads();
#pragma unroll
        for (int kb = 0; kb < 2; ++kb) {
            f16x8 af[4], bf[4];
#pragma unroll
            for (int mt = 0; mt < 4; ++mt)
                af[mt] = *(const f16x8*)(&As[(wm * 64 + mt * 16 + cl) * 72 + kb * 32 + quad * 8]);
#pragma unroll
            for (int nt = 0; nt < 4; ++nt)
                bf[nt] = *(const f16x8*)(&Bs[(wn * 64 + nt * 16 + cl) * 72 + kb * 32 + quad * 8]);
#pragma unroll
            for (int mt = 0; mt < 4; ++mt)
#pragma unroll
                for (int nt = 0; nt < 4; ++nt)
                    acc[mt][nt] = __builtin_amdgcn_mfma_f32_16x16x32_f16(af[mt], bf[nt], acc[mt][nt], 0, 0, 0);
        }
    }

    // bias (bias[col]; all 4 regs of a frag share col)
    float bcol[4];
#pragma unroll
    for (int nt = 0; nt < 4; ++nt) bcol[nt] = bias[bn + wn * 64 + nt * 16 + cl];
#pragma unroll
    for (int mt = 0; mt < 4; ++mt)
#pragma unroll
        for (int nt = 0; nt < 4; ++nt)
#pragma unroll
            for (int rg = 0; rg < 4; ++rg) acc[mt][nt][rg] += bcol[nt];

    if (epi == 0) {                       // fp32 plain store (final projection)
        float* C = (float*)Cout;
#pragma unroll
        for (int mt = 0; mt < 4; ++mt)
#pragma unroll
            for (int rg = 0; rg < 4; ++rg) {
                const int row = bm + wm * 64 + mt * 16 + quad * 4 + rg;
#pragma unroll
                for (int nt = 0; nt < 4; ++nt)
                    C[(size_t)row * EDIM + bn + wn * 64 + nt * 16 + cl] = acc[mt][nt][rg];
            }
    } else if (epi == 1) {                // l2norm over head-dim -> f16 [b,h,s,d]
        f16* C = (f16*)Cout;
#pragma unroll
        for (int mt = 0; mt < 4; ++mt)
#pragma unroll
            for (int rg = 0; rg < 4; ++rg) {
                float ss = 0.f;
#pragma unroll
                for (int nt = 0; nt < 4; ++nt) ss += acc[mt][nt][rg] * acc[mt][nt][rg];
                ss += __shfl_xor(ss, 1); ss += __shfl_xor(ss, 2);
                ss += __shfl_xor(ss, 4); ss += __shfl_xor(ss, 8);
                const float inv = 1.0f / (sqrtf(ss) + 1e-8f);
                const int row = bm + wm * 64 + mt * 16 + quad * 4 + rg;
                const int b = row >> 11, s = row & (SEQ - 1);
#pragma unroll
                for (int nt = 0; nt < 4; ++nt) {
                    const int col = bn + wn * 64 + nt * 16 + cl;
                    const int h = col >> 6, d = col & 63;
                    C[((size_t)(b * NH + h) * SEQ + s) * HD + d] = (f16)(acc[mt][nt][rg] * inv);
                }
            }
    } else {                              // epi==2: V transposed -> f16 [b,h,d,s]
        f16* C = (f16*)Cout;
#pragma unroll
        for (int mt = 0; mt < 4; ++mt) {
            const int s0 = bm + wm * 64 + mt * 16 + quad * 4;
            const int b = s0 >> 11, sl = s0 & (SEQ - 1);
#pragma unroll
            for (int nt = 0; nt < 4; ++nt) {
                const int col = bn + wn * 64 + nt * 16 + cl;
                const int h = col >> 6, d = col & 63;
                f16x4 o = {(f16)acc[mt][nt][0], (f16)acc[mt][nt][1],
                           (f16)acc[mt][nt][2], (f16)acc[mt][nt][3]};
                *(f16x4*)(C + ((size_t)(b * NH + h) * HD + d) * SEQ + sl) = o;
            }
        }
    }
}

// ---------------------------------------------------------------------------
// Yat attention, f16 MFMA, streaming (scores > 0 -> plain sum-normalize).
// Block: 128 q of one (b,h); 4 waves split 2(q) x 2(k). K-tile = 128.
// Per wave: 64q x 64k; Q frags preloaded to regs; P wave-private in LDS
// (region reuses dead Q staging); cross-wk O/rowsum reduce at the end.
// ---------------------------------------------------------------------------
__global__ __launch_bounds__(256)
void yat_attn(const f16* __restrict__ Qh, const f16* __restrict__ Kh,
              const f16* __restrict__ Vt, f16* __restrict__ AO)
{
    __shared__ __align__(16) char lds[56320];
    f16* Qs  = (f16*)lds;                 // 128 x 72 = 18432 B (staging only)
    f16* Ks  = (f16*)(lds + 20480);       // 128 x 72 = 18432 B
    f16* Vts = (f16*)(lds + 38912);       // 64 x 136 = 17408 B

    const int tid  = threadIdx.x;
    const int lane = tid & 63;
    const int w    = tid >> 6;
    const int cl   = lane & 15;
    const int quad = lane >> 4;
    const int wm = w & 1;                 // q half
    const int wk = w >> 1;                // k half
    const int q0 = blockIdx.x * 128;
    const int bh = blockIdx.y;

    const f16* Qg = Qh + (size_t)bh * SEQ * HD;
    const f16* Kg = Kh + (size_t)bh * SEQ * HD;
    const f16* Vg = Vt + (size_t)bh * HD * SEQ;

    const int sr = tid >> 3, sc = tid & 7;    // K/Q staging (128 rows x 8 chunks)
    const int vr = tid >> 4, vc = tid & 15;   // Vt staging (64 rows x 16 chunks)

    // ---- stage Q tile, preload A-fragments to registers ----
#pragma unroll
    for (int i = 0; i < 4; ++i) {
        const int rr = sr + i * 32;
        *(f16x8*)(&Qs[rr * 72 + sc * 8]) =
            *(const f16x8*)(Qg + (size_t)(q0 + rr) * HD + sc * 8);
    }
    __syncthreads();
    f16x8 qf[4][2];
#pragma unroll
    for (int mt = 0; mt < 4; ++mt)
#pragma unroll
        for (int kb = 0; kb < 2; ++kb)
            qf[mt][kb] = *(const f16x8*)(&Qs[(wm * 64 + mt * 16 + cl) * 72 + kb * 32 + quad * 8]);
    __syncthreads();   // all preloads done before P overwrites the Q region

    f16* Pw = (f16*)(lds + w * 5120);     // wave-private P: 64 x 40 f16

    f32x4 O[4][4];
    float rs[4][4];
#pragma unroll
    for (int i = 0; i < 4; ++i)
#pragma unroll
        for (int j = 0; j < 4; ++j) { O[i][j] = (f32x4){0.f, 0.f, 0.f, 0.f}; rs[i][j] = 0.f; }

    for (int t0 = 0; t0 < SEQ; t0 += 128) {
        f16x8 kv[4], vv[4];
#pragma unroll
        for (int i = 0; i < 4; ++i)
            kv[i] = *(const f16x8*)(Kg + (size_t)(t0 + sr + i * 32) * HD + sc * 8);
#pragma unroll
        for (int i = 0; i < 4; ++i)
            vv[i] = *(const f16x8*)(Vg + (size_t)(vr + i * 16) * SEQ + t0 + vc * 8);
        __syncthreads();                  // previous iteration's reads complete
#pragma unroll
        for (int i = 0; i < 4; ++i)
            *(f16x8*)(&Ks[(sr + i * 32) * 72 + sc * 8]) = kv[i];
#pragma unroll
        for (int i = 0; i < 4; ++i)
            *(f16x8*)(&Vts[(vr + i * 16) * 136 + vc * 8]) = vv[i];
        __syncthreads();                  // tiles staged

#pragma unroll
        for (int cch = 0; cch < 2; ++cch) {
            const int kbase = wk * 64 + cch * 32;
            // ---- S = Qn Kn^T (64q x 32k) ----
            f32x4 s[4][2];
#pragma unroll
            for (int i = 0; i < 4; ++i) { s[i][0] = (f32x4){0.f,0.f,0.f,0.f}; s[i][1] = (f32x4){0.f,0.f,0.f,0.f}; }
#pragma unroll
            for (int kb = 0; kb < 2; ++kb) {
                f16x8 bf0 = *(const f16x8*)(&Ks[(kbase +  0 + cl) * 72 + kb * 32 + quad * 8]);
                f16x8 bf1 = *(const f16x8*)(&Ks[(kbase + 16 + cl) * 72 + kb * 32 + quad * 8]);
#pragma unroll
                for (int mt = 0; mt < 4; ++mt) {
                    s[mt][0] = __builtin_amdgcn_mfma_f32_16x16x32_f16(qf[mt][kb], bf0, s[mt][0], 0, 0, 0);
                    s[mt][1] = __builtin_amdgcn_mfma_f32_16x16x32_f16(qf[mt][kb], bf1, s[mt][1], 0, 0, 0);
                }
            }
            // ---- yat scores + row-sum + P -> LDS (wave-private, no barrier) ----
#pragma unroll
            for (int mt = 0; mt < 4; ++mt)
#pragma unroll
                for (int nt = 0; nt < 2; ++nt)
#pragma unroll
                    for (int rg = 0; rg < 4; ++rg) {
                        const float dot = s[mt][nt][rg];
                        float num = 1.0f + dot;
                        num *= num;
                        const float p = num * __builtin_amdgcn_rcpf(1.0f + YAT_EPS - dot);
                        rs[mt][rg] += p;
                        Pw[(mt * 16 + quad * 4 + rg) * 40 + nt * 16 + cl] = (f16)p;
                    }
            // ---- O += P V (kdim = this 32-k chunk) ----
            f16x8 pa[4];
#pragma unroll
            for (int mt = 0; mt < 4; ++mt)
                pa[mt] = *(const f16x8*)(&Pw[(mt * 16 + cl) * 40 + quad * 8]);
#pragma unroll
            for (int dn = 0; dn < 4; ++dn) {
                f16x8 vb = *(const f16x8*)(&Vts[(dn * 16 + cl) * 136 + kbase + quad * 8]);
#pragma unroll
                for (int mt = 0; mt < 4; ++mt)
                    O[mt][dn] = __builtin_amdgcn_mfma_f32_16x16x32_f16(pa[mt], vb, O[mt][dn], 0, 0, 0);
            }
        }
        __syncthreads();                  // compute done before next stage
    }

    // ---- epilogue: cross-wk reduction of row sums and O, normalize, store ----
    float* rs_s = (float*)lds;                  // 2 x 128 fp32
    float* Ox   = (float*)(lds + 20480);        // 128 x 65 fp32 = 33280 B (K+Vt regions)

#pragma unroll
    for (int mt = 0; mt < 4; ++mt)
#pragma unroll
        for (int rg = 0; rg < 4; ++rg) {
            float t = rs[mt][rg];
            t += __shfl_xor(t, 1); t += __shfl_xor(t, 2);
            t += __shfl_xor(t, 4); t += __shfl_xor(t, 8);
            if (cl == 0) rs_s[wk * 128 + wm * 64 + mt * 16 + quad * 4 + rg] = t;
        }
    if (wk == 1) {
#pragma unroll
        for (int mt = 0; mt < 4; ++mt)
#pragma unroll
            for (int dn = 0; dn < 4; ++dn)
#pragma unroll
                for (int rg = 0; rg < 4; ++rg)
                    Ox[(wm * 64 + mt * 16 + quad * 4 + rg) * 65 + dn * 16 + cl] = O[mt][dn][rg];
    }
    __syncthreads();
    if (wk == 0) {
        const int b = bh >> 4, h = bh & 15;
#pragma unroll
        for (int mt = 0; mt < 4; ++mt)
#pragma unroll
            for (int rg = 0; rg < 4; ++rg) {
                const int ql = wm * 64 + mt * 16 + quad * 4 + rg;
                const float tot = rs_s[ql] + rs_s[128 + ql];
                const float inv = 1.0f / (tot + 1e-6f);
                const size_t rowoff = ((size_t)b * SEQ + q0 + ql) * EDIM + h * 64;
#pragma unroll
                for (int dn = 0; dn < 4; ++dn)
                    AO[rowoff + dn * 16 + cl] =
                        (f16)((O[mt][dn][rg] + Ox[ql * 65 + dn * 16 + cl]) * inv);
            }
    }
}

// ---------------------------------------------------------------------------
extern "C" void kernel_launch(void* const* d_in, const int* in_sizes, int n_in,
                              void* d_out, int out_size, void* d_ws, size_t ws_size,
                              hipStream_t stream)
{
    const float* x  = (const float*)d_in[0];
    const float* Wq = (const float*)d_in[1];
    const float* bq = (const float*)d_in[2];
    const float* Wk = (const float*)d_in[3];
    const float* bk = (const float*)d_in[4];
    const float* Wv = (const float*)d_in[5];
    const float* bv = (const float*)d_in[6];
    const float* Wo = (const float*)d_in[7];
    const float* bo = (const float*)d_in[8];

    char* p = (char*)d_ws;
    f16* xb  = (f16*)p;                 p += (size_t)NROW * EDIM * 2;   // 8 MB
    f16* Wqt = (f16*)p;                 p += (size_t)EDIM * EDIM * 2;   // 2 MB
    f16* Wkt = (f16*)p;                 p += (size_t)EDIM * EDIM * 2;
    f16* Wvt = (f16*)p;                 p += (size_t)EDIM * EDIM * 2;
    f16* Wot = (f16*)p;                 p += (size_t)EDIM * EDIM * 2;
    f16* Qhb = (f16*)p;                 p += (size_t)NROW * EDIM * 2;   // [b,h,s,d]
    f16* Khb = (f16*)p;                 p += (size_t)NROW * EDIM * 2;
    f16* Vtb = (f16*)p;                 p += (size_t)NROW * EDIM * 2;   // [b,h,d,s]
    f16* AOb = (f16*)p;                 p += (size_t)NROW * EDIM * 2;   // [b,s,e]

    cast_f16_kernel<<<NROW * EDIM / 1024, 256, 0, stream>>>(x, xb);
    transcast_kernel<<<dim3(32, 32), 256, 0, stream>>>(Wq, Wqt);
    transcast_kernel<<<dim3(32, 32), 256, 0, stream>>>(Wk, Wkt);
    transcast_kernel<<<dim3(32, 32), 256, 0, stream>>>(Wv, Wvt);
    transcast_kernel<<<dim3(32, 32), 256, 0, stream>>>(Wo, Wot);

    const dim3 gg(NROW / 128, EDIM / 128);   // (32, 8)
    gemm_f16<<<gg, 256, 0, stream>>>(xb, Wqt, bq, Qhb, 1);
    gemm_f16<<<gg, 256, 0, stream>>>(xb, Wkt, bk, Khb, 1);
    gemm_f16<<<gg, 256, 0, stream>>>(xb, Wvt, bv, Vtb, 2);

    yat_attn<<<dim3(SEQ / 128, BATCH * NH), 256, 0, stream>>>(Qhb, Khb, Vtb, AOb);

    gemm_f16<<<gg, 256, 0, stream>>>(AOb, Wot, bo, (float*)d_out, 0);
}

// Round 3
// 245.692 us; speedup vs baseline: 5.0328x; 1.1602x over previous
//
#include <hip/hip_runtime.h>
#include <math.h>

#define EDIM 1024
#define NH   16
#define HD   64
#define BATCH 2
#define SEQ  2048
#define NROW (BATCH*SEQ)   // 4096
#define YAT_EPS 0.1f

typedef _Float16 f16;
typedef _Float16 f16x8 __attribute__((ext_vector_type(8)));
typedef _Float16 f16x4 __attribute__((ext_vector_type(4)));
typedef float    f32x4 __attribute__((ext_vector_type(4)));

// async global->LDS, 16B per lane, dest = wave-uniform base + lane*16
#define GLL16(gp, lp) __builtin_amdgcn_global_load_lds( \
    (const __attribute__((address_space(1))) void*)(gp), \
    (__attribute__((address_space(3))) void*)(lp), 16, 0, 0)

// ---------------------------------------------------------------------------
// fp32 -> f16 elementwise cast (x). 4 elems/thread.
// ---------------------------------------------------------------------------
__global__ __launch_bounds__(256)
void cast_f16_kernel(const float* __restrict__ src, f16* __restrict__ dst)
{
    const int i = (blockIdx.x * 256 + threadIdx.x) * 4;
    const float4 v = *(const float4*)(src + i);
    f16x4 o = {(f16)v.x, (f16)v.y, (f16)v.z, (f16)v.w};
    *(f16x4*)(dst + i) = o;
}

// ---------------------------------------------------------------------------
// W [1024 k][1024 n] fp32  ->  Wt [1024 n][1024 k] f16  (32x32 LDS transpose)
// ---------------------------------------------------------------------------
__global__ __launch_bounds__(256)
void transcast_kernel(const float* __restrict__ W, f16* __restrict__ Wt)
{
    __shared__ float T[32][33];
    const int t = threadIdx.x;
    const int r = t >> 3, c4 = (t & 7) * 4;
    const int bi = blockIdx.x * 32, bj = blockIdx.y * 32;
    const float4 v = *(const float4*)(W + (size_t)(bi + r) * 1024 + bj + c4);
    T[r][c4 + 0] = v.x; T[r][c4 + 1] = v.y; T[r][c4 + 2] = v.z; T[r][c4 + 3] = v.w;
    __syncthreads();
    f16x4 o = {(f16)T[c4 + 0][r], (f16)T[c4 + 1][r], (f16)T[c4 + 2][r], (f16)T[c4 + 3][r]};
    *(f16x4*)(Wt + (size_t)(bj + r) * 1024 + bi + c4) = o;
}

// ---------------------------------------------------------------------------
// MFMA GEMM, m97-style: global_load_lds (16B, XOR-swizzled) staging.
// C = A[4096,1024] @ Bt[n][k]^T + bias. 128x128 tile, BK=64, 4 waves 2x2.
// blockIdx.z selects one of 3 (Bt,bias,out,epi) sets (fused QKV).
// LDS rows unpadded (128B); chunk swizzle c^(row&7) -> conflict-free frags.
// epi: 0 = fp32 [M,N]; 1 = l2norm -> f16 [b,h,s,d]; 2 = f16 [b,h,d,s].
// ---------------------------------------------------------------------------
__global__ __launch_bounds__(256)
void gemm_f16(const f16* __restrict__ A,
              const f16* __restrict__ B0, const f16* __restrict__ B1, const f16* __restrict__ B2,
              const float* __restrict__ bi0, const float* __restrict__ bi1, const float* __restrict__ bi2,
              void* __restrict__ o0, void* __restrict__ o1, void* __restrict__ o2,
              int e0, int e1, int e2)
{
    __shared__ __align__(16) f16 As[128 * 64];
    __shared__ __align__(16) f16 Bs[128 * 64];

    const int z = blockIdx.z;
    const f16*   Bt   = (z == 0) ? B0  : (z == 1) ? B1  : B2;
    const float* bias = (z == 0) ? bi0 : (z == 1) ? bi1 : bi2;
    void*        Cout = (z == 0) ? o0  : (z == 1) ? o1  : o2;
    const int    epi  = (z == 0) ? e0  : (z == 1) ? e1  : e2;

    const int tid  = threadIdx.x;
    const int lane = tid & 63;
    const int w    = tid >> 6;
    const int cl   = lane & 15;
    const int quad = lane >> 4;
    const int wm = w & 1, wn = w >> 1;
    const int bm = blockIdx.x * 128, bn = blockIdx.y * 128;

    // staging lane constants: wave w stages rows {w*8..w*8+7} + it*32
    const int srow = w * 8 + (lane >> 3);        // 0..31
    const int scs  = (lane & 7) ^ (lane >> 3);   // swizzled source chunk
    const f16* gA = A  + (size_t)(bm + srow) * 1024 + scs * 8;
    const f16* gB = Bt + (size_t)(bn + srow) * 1024 + scs * 8;
    f16* lA = As + w * 512;                      // byte offset w*1024
    f16* lB = Bs + w * 512;

    f32x4 acc[4][4];
#pragma unroll
    for (int i = 0; i < 4; ++i)
#pragma unroll
        for (int j = 0; j < 4; ++j) acc[i][j] = (f32x4){0.f, 0.f, 0.f, 0.f};

    for (int k0 = 0; k0 < 1024; k0 += 64) {
        __syncthreads();                          // prev tile reads done
#pragma unroll
        for (int it = 0; it < 4; ++it) {
            GLL16(gA + (size_t)it * 32 * 1024 + k0, lA + it * 2048);
            GLL16(gB + (size_t)it * 32 * 1024 + k0, lB + it * 2048);
        }
        __syncthreads();                          // vmcnt(0) drain: tiles ready
#pragma unroll
        for (int kb = 0; kb < 2; ++kb) {
            f16x8 af[4], bf[4];
#pragma unroll
            for (int mt = 0; mt < 4; ++mt)
                af[mt] = *(const f16x8*)(&As[(wm * 64 + mt * 16 + cl) * 64 +
                                             (((kb * 4 + quad) ^ (cl & 7)) * 8)]);
#pragma unroll
            for (int nt = 0; nt < 4; ++nt)
                bf[nt] = *(const f16x8*)(&Bs[(wn * 64 + nt * 16 + cl) * 64 +
                                             (((kb * 4 + quad) ^ (cl & 7)) * 8)]);
#pragma unroll
            for (int mt = 0; mt < 4; ++mt)
#pragma unroll
                for (int nt = 0; nt < 4; ++nt)
                    acc[mt][nt] = __builtin_amdgcn_mfma_f32_16x16x32_f16(af[mt], bf[nt], acc[mt][nt], 0, 0, 0);
        }
    }

    float bcol[4];
#pragma unroll
    for (int nt = 0; nt < 4; ++nt) bcol[nt] = bias[bn + wn * 64 + nt * 16 + cl];
#pragma unroll
    for (int mt = 0; mt < 4; ++mt)
#pragma unroll
        for (int nt = 0; nt < 4; ++nt)
#pragma unroll
            for (int rg = 0; rg < 4; ++rg) acc[mt][nt][rg] += bcol[nt];

    if (epi == 0) {
        float* C = (float*)Cout;
#pragma unroll
        for (int mt = 0; mt < 4; ++mt)
#pragma unroll
            for (int rg = 0; rg < 4; ++rg) {
                const int row = bm + wm * 64 + mt * 16 + quad * 4 + rg;
#pragma unroll
                for (int nt = 0; nt < 4; ++nt)
                    C[(size_t)row * EDIM + bn + wn * 64 + nt * 16 + cl] = acc[mt][nt][rg];
            }
    } else if (epi == 1) {                // l2norm over head-dim -> f16 [b,h,s,d]
        f16* C = (f16*)Cout;
#pragma unroll
        for (int mt = 0; mt < 4; ++mt)
#pragma unroll
            for (int rg = 0; rg < 4; ++rg) {
                float ss = 0.f;
#pragma unroll
                for (int nt = 0; nt < 4; ++nt) ss += acc[mt][nt][rg] * acc[mt][nt][rg];
                ss += __shfl_xor(ss, 1); ss += __shfl_xor(ss, 2);
                ss += __shfl_xor(ss, 4); ss += __shfl_xor(ss, 8);
                const float inv = 1.0f / (sqrtf(ss) + 1e-8f);
                const int row = bm + wm * 64 + mt * 16 + quad * 4 + rg;
                const int b = row >> 11, s = row & (SEQ - 1);
#pragma unroll
                for (int nt = 0; nt < 4; ++nt) {
                    const int col = bn + wn * 64 + nt * 16 + cl;
                    const int h = col >> 6, d = col & 63;
                    C[((size_t)(b * NH + h) * SEQ + s) * HD + d] = (f16)(acc[mt][nt][rg] * inv);
                }
            }
    } else {                              // epi==2: V transposed -> f16 [b,h,d,s]
        f16* C = (f16*)Cout;
#pragma unroll
        for (int mt = 0; mt < 4; ++mt) {
            const int s0 = bm + wm * 64 + mt * 16 + quad * 4;
            const int b = s0 >> 11, sl = s0 & (SEQ - 1);
#pragma unroll
            for (int nt = 0; nt < 4; ++nt) {
                const int col = bn + wn * 64 + nt * 16 + cl;
                const int h = col >> 6, d = col & 63;
                f16x4 o = {(f16)acc[mt][nt][0], (f16)acc[mt][nt][1],
                           (f16)acc[mt][nt][2], (f16)acc[mt][nt][3]};
                *(f16x4*)(C + ((size_t)(b * NH + h) * HD + d) * SEQ + sl) = o;
            }
        }
    }
}

// ---------------------------------------------------------------------------
// Yat attention, S^T formulation + global_load_lds staging.
// Block: 128 q of one (b,h); 4 waves = 2(q-half wm) x 2(k-half wk).
// S^T = K·Q^T  -> C-layout lane holds 4 consecutive k for one q
//              -> P store is packed ds_write_b64 into P[q][k] layout.
// O = P·V with V^T [d][s] as B operand. All tiles via swizzled global_load_lds.
// LDS 53248 B: region0 20480 (Q stage 16K -> wave-private P 4x5120),
//              Ks 16K @20480, Vts 16K @36864.
// ---------------------------------------------------------------------------
__global__ __launch_bounds__(256)
void yat_attn(const f16* __restrict__ Qh, const f16* __restrict__ Kh,
              const f16* __restrict__ Vt, f16* __restrict__ AO)
{
    __shared__ __align__(16) char lds[53248];
    f16* Ks  = (f16*)(lds + 20480);
    f16* Vts = (f16*)(lds + 36864);

    const int tid  = threadIdx.x;
    const int lane = tid & 63;
    const int w    = tid >> 6;
    const int cl   = lane & 15;
    const int quad = lane >> 4;
    const int wm = w & 1;                 // q half
    const int wk = w >> 1;                // k half
    const int q0 = blockIdx.x * 128;
    const int bh = blockIdx.y;

    const f16* Qg = Qh + (size_t)bh * SEQ * HD;
    const f16* Kg = Kh + (size_t)bh * SEQ * HD;
    const f16* Vg = Vt + (size_t)bh * HD * SEQ;

    // staging lane constants
    const int krow = w * 8 + (lane >> 3);            // 0..31 (rows of 64-f16)
    const int kcs  = (lane & 7) ^ (lane >> 3);       // chunk swizzle ^(row&7)
    const int vrow = w * 4 + (lane >> 4);            // 0..15 (rows of 128-f16)
    const int vcs  = (lane & 15) ^ vrow;             // chunk swizzle ^(row&15)

    // ---- stage Q (swizzled), preload B-fragments ----
    {
        const f16* gQ = Qg + (size_t)(q0 + krow) * HD + kcs * 8;
        f16* lQ = (f16*)lds + w * 512;
#pragma unroll
        for (int it = 0; it < 4; ++it)
            GLL16(gQ + it * 32 * HD, lQ + it * 2048);
    }
    __syncthreads();
    f16x8 qf[4][2];
#pragma unroll
    for (int qt = 0; qt < 4; ++qt)
#pragma unroll
        for (int kb = 0; kb < 2; ++kb)
            qf[qt][kb] = *(const f16x8*)((f16*)lds + (wm * 64 + qt * 16 + cl) * 64 +
                                         ((kb * 4 + quad) ^ (cl & 7)) * 8);
    __syncthreads();                       // preloads done before P overwrites

    f16* Pw = (f16*)(lds + w * 5120);      // wave-private P: 64 x 40 f16

    f32x4 O[4][4];
    float rs[4] = {0.f, 0.f, 0.f, 0.f};
#pragma unroll
    for (int i = 0; i < 4; ++i)
#pragma unroll
        for (int j = 0; j < 4; ++j) O[i][j] = (f32x4){0.f, 0.f, 0.f, 0.f};

    const f16* gK = Kg + (size_t)krow * HD + kcs * 8;
    const f16* gV = Vg + (size_t)vrow * SEQ + vcs * 8;
    f16* lK = Ks  + w * 512;
    f16* lV = Vts + w * 512;

    for (int t0 = 0; t0 < SEQ; t0 += 128) {
        __syncthreads();                   // prev tile reads done
#pragma unroll
        for (int it = 0; it < 4; ++it) {
            GLL16(gK + (size_t)(t0 + it * 32) * HD, lK + it * 2048);
            GLL16(gV + (size_t)(it * 16) * SEQ + t0, lV + it * 2048);
        }
        __syncthreads();                   // vmcnt(0) drain: K,V staged

#pragma unroll
        for (int cch = 0; cch < 2; ++cch) {
            const int kbase = wk * 64 + cch * 32;
            // ---- S^T (32k x 64q) = K·Q^T ----
            f32x4 s[2][4];
#pragma unroll
            for (int kt = 0; kt < 2; ++kt)
#pragma unroll
                for (int qt = 0; qt < 4; ++qt) s[kt][qt] = (f32x4){0.f, 0.f, 0.f, 0.f};
#pragma unroll
            for (int kb = 0; kb < 2; ++kb) {
                const int sw = ((kb * 4 + quad) ^ (cl & 7)) * 8;
                f16x8 af0 = *(const f16x8*)(&Ks[(kbase +  0 + cl) * 64 + sw]);
                f16x8 af1 = *(const f16x8*)(&Ks[(kbase + 16 + cl) * 64 + sw]);
#pragma unroll
                for (int qt = 0; qt < 4; ++qt) {
                    s[0][qt] = __builtin_amdgcn_mfma_f32_16x16x32_f16(af0, qf[qt][kb], s[0][qt], 0, 0, 0);
                    s[1][qt] = __builtin_amdgcn_mfma_f32_16x16x32_f16(af1, qf[qt][kb], s[1][qt], 0, 0, 0);
                }
            }
            // ---- yat scores; packed P store (4 consecutive k per lane) ----
#pragma unroll
            for (int kt = 0; kt < 2; ++kt)
#pragma unroll
                for (int qt = 0; qt < 4; ++qt) {
                    f16x4 pk;
                    float psum = 0.f;
#pragma unroll
                    for (int rg = 0; rg < 4; ++rg) {
                        const float dot = s[kt][qt][rg];
                        float num = 1.0f + dot; num *= num;
                        const float p = num * __builtin_amdgcn_rcpf(1.0f + YAT_EPS - dot);
                        psum += p;
                        pk[rg] = (f16)p;
                    }
                    rs[qt] += psum;
                    *(f16x4*)(&Pw[(qt * 16 + cl) * 40 + kt * 16 + quad * 4]) = pk;
                }
            // ---- O += P·V over this 32-k chunk ----
            f16x8 pa[4];
#pragma unroll
            for (int qt = 0; qt < 4; ++qt)
                pa[qt] = *(const f16x8*)(&Pw[(qt * 16 + cl) * 40 + quad * 8]);
#pragma unroll
            for (int dn = 0; dn < 4; ++dn) {
                f16x8 vb = *(const f16x8*)(&Vts[(dn * 16 + cl) * 128 +
                                                ((wk * 8 + cch * 4 + quad) ^ cl) * 8]);
#pragma unroll
                for (int qt = 0; qt < 4; ++qt)
                    O[qt][dn] = __builtin_amdgcn_mfma_f32_16x16x32_f16(pa[qt], vb, O[qt][dn], 0, 0, 0);
            }
        }
    }

    // ---- epilogue: cross-wk reduce rs and O, normalize, store ----
    __syncthreads();
    float* rs_s = (float*)lds;                 // 256 f32 (region0 dead)
    float* Ox   = (float*)(lds + 20480);       // 128 x 64 f32 (Ks+Vts dead)

#pragma unroll
    for (int qt = 0; qt < 4; ++qt) {
        float t = rs[qt];
        t += __shfl_xor(t, 16);
        t += __shfl_xor(t, 32);
        if (quad == 0) rs_s[wk * 128 + wm * 64 + qt * 16 + cl] = t;
    }
    if (wk == 1) {
#pragma unroll
        for (int qt = 0; qt < 4; ++qt)
#pragma unroll
            for (int dn = 0; dn < 4; ++dn)
#pragma unroll
                for (int rg = 0; rg < 4; ++rg)
                    Ox[(wm * 64 + qt * 16 + quad * 4 + rg) * 64 + dn * 16 + cl] = O[qt][dn][rg];
    }
    __syncthreads();
    if (wk == 0) {
        const int b = bh >> 4, h = bh & 15;
#pragma unroll
        for (int qt = 0; qt < 4; ++qt)
#pragma unroll
            for (int rg = 0; rg < 4; ++rg) {
                const int ql = wm * 64 + qt * 16 + quad * 4 + rg;
                const float tot = rs_s[ql] + rs_s[128 + ql];
                const float inv = 1.0f / (tot + 1e-6f);
                const size_t rowoff = ((size_t)b * SEQ + q0 + ql) * EDIM + h * 64;
#pragma unroll
                for (int dn = 0; dn < 4; ++dn)
                    AO[rowoff + dn * 16 + cl] =
                        (f16)((O[qt][dn][rg] + Ox[ql * 64 + dn * 16 + cl]) * inv);
            }
    }
}

// ---------------------------------------------------------------------------
extern "C" void kernel_launch(void* const* d_in, const int* in_sizes, int n_in,
                              void* d_out, int out_size, void* d_ws, size_t ws_size,
                              hipStream_t stream)
{
    const float* x  = (const float*)d_in[0];
    const float* Wq = (const float*)d_in[1];
    const float* bq = (const float*)d_in[2];
    const float* Wk = (const float*)d_in[3];
    const float* bk = (const float*)d_in[4];
    const float* Wv = (const float*)d_in[5];
    const float* bv = (const float*)d_in[6];
    const float* Wo = (const float*)d_in[7];
    const float* bo = (const float*)d_in[8];

    char* p = (char*)d_ws;
    f16* xb  = (f16*)p;                 p += (size_t)NROW * EDIM * 2;   // 8 MB
    f16* Wqt = (f16*)p;                 p += (size_t)EDIM * EDIM * 2;   // 2 MB
    f16* Wkt = (f16*)p;                 p += (size_t)EDIM * EDIM * 2;
    f16* Wvt = (f16*)p;                 p += (size_t)EDIM * EDIM * 2;
    f16* Wot = (f16*)p;                 p += (size_t)EDIM * EDIM * 2;
    f16* Qhb = (f16*)p;                 p += (size_t)NROW * EDIM * 2;   // [b,h,s,d]
    f16* Khb = (f16*)p;                 p += (size_t)NROW * EDIM * 2;
    f16* Vtb = (f16*)p;                 p += (size_t)NROW * EDIM * 2;   // [b,h,d,s]
    f16* AOb = (f16*)p;                 p += (size_t)NROW * EDIM * 2;   // [b,s,e]

    cast_f16_kernel<<<NROW * EDIM / 1024, 256, 0, stream>>>(x, xb);
    transcast_kernel<<<dim3(32, 32), 256, 0, stream>>>(Wq, Wqt);
    transcast_kernel<<<dim3(32, 32), 256, 0, stream>>>(Wk, Wkt);
    transcast_kernel<<<dim3(32, 32), 256, 0, stream>>>(Wv, Wvt);
    transcast_kernel<<<dim3(32, 32), 256, 0, stream>>>(Wo, Wot);

    // fused Q/K/V projections: 768 blocks = 3 blocks/CU
    gemm_f16<<<dim3(NROW / 128, EDIM / 128, 3), 256, 0, stream>>>(
        xb, Wqt, Wkt, Wvt, bq, bk, bv, Qhb, Khb, Vtb, 1, 1, 2);

    yat_attn<<<dim3(SEQ / 128, BATCH * NH), 256, 0, stream>>>(Qhb, Khb, Vtb, AOb);

    gemm_f16<<<dim3(NROW / 128, EDIM / 128, 1), 256, 0, stream>>>(
        AOb, Wot, Wot, Wot, bo, bo, bo, d_out, d_out, d_out, 0, 0, 0);
}

// Round 4
// 210.733 us; speedup vs baseline: 5.8676x; 1.1659x over previous
//
#include <hip/hip_runtime.h>
#include <math.h>

#define EDIM 1024
#define NH   16
#define HD   64
#define BATCH 2
#define SEQ  2048
#define NROW (BATCH*SEQ)   // 4096
#define YAT_EPS 0.1f

typedef _Float16 f16;
typedef _Float16 f16x8 __attribute__((ext_vector_type(8)));
typedef _Float16 f16x4 __attribute__((ext_vector_type(4)));
typedef float    f32x4 __attribute__((ext_vector_type(4)));

// async global->LDS, 16B per lane, dest = wave-uniform base + lane*16
#define GLL16(gp, lp) __builtin_amdgcn_global_load_lds( \
    (const __attribute__((address_space(1))) void*)(gp), \
    (__attribute__((address_space(3))) void*)(lp), 16, 0, 0)

// ---------------------------------------------------------------------------
// fp32 -> f16 elementwise cast (x). 4 elems/thread.
// ---------------------------------------------------------------------------
__global__ __launch_bounds__(256)
void cast_f16_kernel(const float* __restrict__ src, f16* __restrict__ dst)
{
    const int i = (blockIdx.x * 256 + threadIdx.x) * 4;
    const float4 v = *(const float4*)(src + i);
    f16x4 o = {(f16)v.x, (f16)v.y, (f16)v.z, (f16)v.w};
    *(f16x4*)(dst + i) = o;
}

// ---------------------------------------------------------------------------
// W [1024 k][1024 n] fp32  ->  Wt [1024 n][1024 k] f16  (32x32 LDS transpose)
// ---------------------------------------------------------------------------
__global__ __launch_bounds__(256)
void transcast_kernel(const float* __restrict__ W, f16* __restrict__ Wt)
{
    __shared__ float T[32][33];
    const int t = threadIdx.x;
    const int r = t >> 3, c4 = (t & 7) * 4;
    const int bi = blockIdx.x * 32, bj = blockIdx.y * 32;
    const float4 v = *(const float4*)(W + (size_t)(bi + r) * 1024 + bj + c4);
    T[r][c4 + 0] = v.x; T[r][c4 + 1] = v.y; T[r][c4 + 2] = v.z; T[r][c4 + 3] = v.w;
    __syncthreads();
    f16x4 o = {(f16)T[c4 + 0][r], (f16)T[c4 + 1][r], (f16)T[c4 + 2][r], (f16)T[c4 + 3][r]};
    *(f16x4*)(Wt + (size_t)(bj + r) * 1024 + bi + c4) = o;
}

// ---------------------------------------------------------------------------
// MFMA GEMM, m97-style: global_load_lds (16B, XOR-swizzled) staging.
// (unchanged from round 3)
// ---------------------------------------------------------------------------
__global__ __launch_bounds__(256)
void gemm_f16(const f16* __restrict__ A,
              const f16* __restrict__ B0, const f16* __restrict__ B1, const f16* __restrict__ B2,
              const float* __restrict__ bi0, const float* __restrict__ bi1, const float* __restrict__ bi2,
              void* __restrict__ o0, void* __restrict__ o1, void* __restrict__ o2,
              int e0, int e1, int e2)
{
    __shared__ __align__(16) f16 As[128 * 64];
    __shared__ __align__(16) f16 Bs[128 * 64];

    const int z = blockIdx.z;
    const f16*   Bt   = (z == 0) ? B0  : (z == 1) ? B1  : B2;
    const float* bias = (z == 0) ? bi0 : (z == 1) ? bi1 : bi2;
    void*        Cout = (z == 0) ? o0  : (z == 1) ? o1  : o2;
    const int    epi  = (z == 0) ? e0  : (z == 1) ? e1  : e2;

    const int tid  = threadIdx.x;
    const int lane = tid & 63;
    const int w    = tid >> 6;
    const int cl   = lane & 15;
    const int quad = lane >> 4;
    const int wm = w & 1, wn = w >> 1;
    const int bm = blockIdx.x * 128, bn = blockIdx.y * 128;

    const int srow = w * 8 + (lane >> 3);        // 0..31
    const int scs  = (lane & 7) ^ (lane >> 3);   // swizzled source chunk
    const f16* gA = A  + (size_t)(bm + srow) * 1024 + scs * 8;
    const f16* gB = Bt + (size_t)(bn + srow) * 1024 + scs * 8;
    f16* lA = As + w * 512;
    f16* lB = Bs + w * 512;

    f32x4 acc[4][4];
#pragma unroll
    for (int i = 0; i < 4; ++i)
#pragma unroll
        for (int j = 0; j < 4; ++j) acc[i][j] = (f32x4){0.f, 0.f, 0.f, 0.f};

    for (int k0 = 0; k0 < 1024; k0 += 64) {
        __syncthreads();
#pragma unroll
        for (int it = 0; it < 4; ++it) {
            GLL16(gA + (size_t)it * 32 * 1024 + k0, lA + it * 2048);
            GLL16(gB + (size_t)it * 32 * 1024 + k0, lB + it * 2048);
        }
        __syncthreads();
#pragma unroll
        for (int kb = 0; kb < 2; ++kb) {
            f16x8 af[4], bf[4];
#pragma unroll
            for (int mt = 0; mt < 4; ++mt)
                af[mt] = *(const f16x8*)(&As[(wm * 64 + mt * 16 + cl) * 64 +
                                             (((kb * 4 + quad) ^ (cl & 7)) * 8)]);
#pragma unroll
            for (int nt = 0; nt < 4; ++nt)
                bf[nt] = *(const f16x8*)(&Bs[(wn * 64 + nt * 16 + cl) * 64 +
                                             (((kb * 4 + quad) ^ (cl & 7)) * 8)]);
#pragma unroll
            for (int mt = 0; mt < 4; ++mt)
#pragma unroll
                for (int nt = 0; nt < 4; ++nt)
                    acc[mt][nt] = __builtin_amdgcn_mfma_f32_16x16x32_f16(af[mt], bf[nt], acc[mt][nt], 0, 0, 0);
        }
    }

    float bcol[4];
#pragma unroll
    for (int nt = 0; nt < 4; ++nt) bcol[nt] = bias[bn + wn * 64 + nt * 16 + cl];
#pragma unroll
    for (int mt = 0; mt < 4; ++mt)
#pragma unroll
        for (int nt = 0; nt < 4; ++nt)
#pragma unroll
            for (int rg = 0; rg < 4; ++rg) acc[mt][nt][rg] += bcol[nt];

    if (epi == 0) {
        float* C = (float*)Cout;
#pragma unroll
        for (int mt = 0; mt < 4; ++mt)
#pragma unroll
            for (int rg = 0; rg < 4; ++rg) {
                const int row = bm + wm * 64 + mt * 16 + quad * 4 + rg;
#pragma unroll
                for (int nt = 0; nt < 4; ++nt)
                    C[(size_t)row * EDIM + bn + wn * 64 + nt * 16 + cl] = acc[mt][nt][rg];
            }
    } else if (epi == 1) {                // l2norm over head-dim -> f16 [b,h,s,d]
        f16* C = (f16*)Cout;
#pragma unroll
        for (int mt = 0; mt < 4; ++mt)
#pragma unroll
            for (int rg = 0; rg < 4; ++rg) {
                float ss = 0.f;
#pragma unroll
                for (int nt = 0; nt < 4; ++nt) ss += acc[mt][nt][rg] * acc[mt][nt][rg];
                ss += __shfl_xor(ss, 1); ss += __shfl_xor(ss, 2);
                ss += __shfl_xor(ss, 4); ss += __shfl_xor(ss, 8);
                const float inv = 1.0f / (sqrtf(ss) + 1e-8f);
                const int row = bm + wm * 64 + mt * 16 + quad * 4 + rg;
                const int b = row >> 11, s = row & (SEQ - 1);
#pragma unroll
                for (int nt = 0; nt < 4; ++nt) {
                    const int col = bn + wn * 64 + nt * 16 + cl;
                    const int h = col >> 6, d = col & 63;
                    C[((size_t)(b * NH + h) * SEQ + s) * HD + d] = (f16)(acc[mt][nt][rg] * inv);
                }
            }
    } else {                              // epi==2: V transposed -> f16 [b,h,d,s]
        f16* C = (f16*)Cout;
#pragma unroll
        for (int mt = 0; mt < 4; ++mt) {
            const int s0 = bm + wm * 64 + mt * 16 + quad * 4;
            const int b = s0 >> 11, sl = s0 & (SEQ - 1);
#pragma unroll
            for (int nt = 0; nt < 4; ++nt) {
                const int col = bn + wn * 64 + nt * 16 + cl;
                const int h = col >> 6, d = col & 63;
                f16x4 o = {(f16)acc[mt][nt][0], (f16)acc[mt][nt][1],
                           (f16)acc[mt][nt][2], (f16)acc[mt][nt][3]};
                *(f16x4*)(C + ((size_t)(b * NH + h) * HD + d) * SEQ + sl) = o;
            }
        }
    }
}

// ---------------------------------------------------------------------------
// Yat attention, round 4: single-barrier double-buffered K/V pipeline.
// Block: 128 q of one (b,h); 4 waves = 2(q-half wm) x 2(k-half wk).
// k-tile = 64 (dbuf x2). Per t0 iter: issue GLL prefetch for t0+64 into
// buf^1, compute on buf, ONE barrier (drains prefetch + retires compute).
// S^T = K.Q^T; polynomial yat score p = 4.41*rcp(u) + (u - 4.2), u=1.1-d.
// LDS 53248: region0 20480 (Q stage 16K -> wave-private P 4x5120),
//            Kbuf 2x8192 @20480, Vbuf 2x8192 @36864.
// ---------------------------------------------------------------------------
__global__ __launch_bounds__(256)
void yat_attn(const f16* __restrict__ Qh, const f16* __restrict__ Kh,
              const f16* __restrict__ Vt, f16* __restrict__ AO)
{
    __shared__ __align__(16) char lds[53248];
    f16* KsB = (f16*)(lds + 20480);       // 2 bufs x 4096 f16
    f16* VsB = (f16*)(lds + 36864);

    const int tid  = threadIdx.x;
    const int lane = tid & 63;
    const int w    = tid >> 6;
    const int cl   = lane & 15;
    const int quad = lane >> 4;
    const int wm = w & 1;                 // q half
    const int wk = w >> 1;                // k half
    const int q0 = blockIdx.x * 128;
    const int bh = blockIdx.y;

    const f16* Qg = Qh + (size_t)bh * SEQ * HD;
    const f16* Kg = Kh + (size_t)bh * SEQ * HD;
    const f16* Vg = Vt + (size_t)bh * HD * SEQ;

    // staging lane constants (rows of 128 B = 64 f16; 8 rows per GLL)
    const int g8   = lane >> 3;                      // 0..7
    const int scs  = (lane & 7) ^ g8;                // chunk swizzle ^(row&7)
    const int qrow = w * 8 + g8;                     // Q staging rows (+it*32)
    const int krow = w * 16 + g8;                    // K/V staging rows (+it*8)

    // ---- stage Q (swizzled), preload B-fragments ----
    {
        const f16* gQ = Qg + (size_t)(q0 + qrow) * HD + scs * 8;
        f16* lQ = (f16*)lds + w * 512;
#pragma unroll
        for (int it = 0; it < 4; ++it)
            GLL16(gQ + it * 32 * HD, lQ + it * 2048);
    }
    __syncthreads();
    f16x8 qf[4][2];
#pragma unroll
    for (int qt = 0; qt < 4; ++qt)
#pragma unroll
        for (int kb = 0; kb < 2; ++kb)
            qf[qt][kb] = *(const f16x8*)((f16*)lds + (wm * 64 + qt * 16 + cl) * 64 +
                                         ((kb * 4 + quad) ^ (cl & 7)) * 8);
    __syncthreads();                       // preloads done before P overwrites

    f16* Pw = (f16*)(lds + w * 5120);      // wave-private P: 64 q x 40 f16 (32+pad)

    f32x4 O[4][4];
    float rs[4] = {0.f, 0.f, 0.f, 0.f};
#pragma unroll
    for (int i = 0; i < 4; ++i)
#pragma unroll
        for (int j = 0; j < 4; ++j) O[i][j] = (f32x4){0.f, 0.f, 0.f, 0.f};

    const f16* gK = Kg + (size_t)krow * HD + scs * 8;      // + t0*HD + it*8*HD
    const f16* gV = Vg + (size_t)krow * SEQ + scs * 8;     // + t0     + it*8*SEQ
    f16* lK = KsB + w * 1024;                              // + buf*4096 + it*512
    f16* lV = VsB + w * 1024;

    // initial prefetch: tile 0 -> buf 0
#pragma unroll
    for (int it = 0; it < 2; ++it) {
        GLL16(gK + (size_t)(it * 8) * HD, lK + it * 512);
        GLL16(gV + (size_t)(it * 8) * SEQ, lV + it * 512);
    }

    for (int t0 = 0; t0 < SEQ; t0 += 64) {
        const int buf = (t0 >> 6) & 1;
        __syncthreads();                   // publishes tile t0, retires t0-1 compute

        if (t0 + 64 < SEQ) {               // prefetch t0+64 into buf^1
            const int nb = buf ^ 1;
#pragma unroll
            for (int it = 0; it < 2; ++it) {
                GLL16(gK + (size_t)(t0 + 64 + it * 8) * HD, lK + nb * 4096 + it * 512);
                GLL16(gV + (size_t)(it * 8) * SEQ + t0 + 64, lV + nb * 4096 + it * 512);
            }
        }

        const f16* Ks = KsB + buf * 4096;
        const f16* Vs = VsB + buf * 4096;

        // ---- S^T (32k x 64q) = K.Q^T over this wave's wk 32-k half ----
        f32x4 s[2][4];
#pragma unroll
        for (int kt = 0; kt < 2; ++kt)
#pragma unroll
            for (int qt = 0; qt < 4; ++qt) s[kt][qt] = (f32x4){0.f, 0.f, 0.f, 0.f};
#pragma unroll
        for (int kb = 0; kb < 2; ++kb) {
            const int sw = ((kb * 4 + quad) ^ (cl & 7)) * 8;
            f16x8 af0 = *(const f16x8*)(&Ks[(wk * 32 +  0 + cl) * 64 + sw]);
            f16x8 af1 = *(const f16x8*)(&Ks[(wk * 32 + 16 + cl) * 64 + sw]);
#pragma unroll
            for (int qt = 0; qt < 4; ++qt) {
                s[0][qt] = __builtin_amdgcn_mfma_f32_16x16x32_f16(af0, qf[qt][kb], s[0][qt], 0, 0, 0);
                s[1][qt] = __builtin_amdgcn_mfma_f32_16x16x32_f16(af1, qf[qt][kb], s[1][qt], 0, 0, 0);
            }
        }

        // ---- yat scores (polynomial) + packed P store ----
#pragma unroll
        for (int kt = 0; kt < 2; ++kt)
#pragma unroll
            for (int qt = 0; qt < 4; ++qt) {
                f16x4 pk;
                float psum = 0.f;
#pragma unroll
                for (int rg = 0; rg < 4; ++rg) {
                    const float u = (1.0f + YAT_EPS) - s[kt][qt][rg];
                    const float p = fmaf(4.41f, __builtin_amdgcn_rcpf(u), u - 4.2f);
                    psum += p;
                    pk[rg] = (f16)p;
                }
                rs[qt] += psum;
                *(f16x4*)(&Pw[(qt * 16 + cl) * 40 + kt * 16 + quad * 4]) = pk;
            }

        // ---- O += P.V over this 32-k chunk ----
        f16x8 pa[4];
#pragma unroll
        for (int qt = 0; qt < 4; ++qt)
            pa[qt] = *(const f16x8*)(&Pw[(qt * 16 + cl) * 40 + quad * 8]);
#pragma unroll
        for (int dn = 0; dn < 4; ++dn) {
            f16x8 vb = *(const f16x8*)(&Vs[(dn * 16 + cl) * 64 +
                                           ((wk * 4 + quad) ^ (cl & 7)) * 8]);
#pragma unroll
            for (int qt = 0; qt < 4; ++qt)
                O[qt][dn] = __builtin_amdgcn_mfma_f32_16x16x32_f16(pa[qt], vb, O[qt][dn], 0, 0, 0);
        }
    }

    // ---- epilogue: cross-wk reduce rs and O, normalize, store ----
    __syncthreads();
    float* rs_s = (float*)lds;                 // 256 f32 (region0 dead)
    float* Ox   = (float*)(lds + 20480);       // 128 x 64 f32 (K/V bufs dead)

#pragma unroll
    for (int qt = 0; qt < 4; ++qt) {
        float t = rs[qt];
        t += __shfl_xor(t, 16);
        t += __shfl_xor(t, 32);
        if (quad == 0) rs_s[wk * 128 + wm * 64 + qt * 16 + cl] = t;
    }
    if (wk == 1) {
#pragma unroll
        for (int qt = 0; qt < 4; ++qt)
#pragma unroll
            for (int dn = 0; dn < 4; ++dn)
#pragma unroll
                for (int rg = 0; rg < 4; ++rg)
                    Ox[(wm * 64 + qt * 16 + quad * 4 + rg) * 64 + dn * 16 + cl] = O[qt][dn][rg];
    }
    __syncthreads();
    if (wk == 0) {
        const int b = bh >> 4, h = bh & 15;
#pragma unroll
        for (int qt = 0; qt < 4; ++qt)
#pragma unroll
            for (int rg = 0; rg < 4; ++rg) {
                const int ql = wm * 64 + qt * 16 + quad * 4 + rg;
                const float tot = rs_s[ql] + rs_s[128 + ql];
                const float inv = 1.0f / (tot + 1e-6f);
                const size_t rowoff = ((size_t)b * SEQ + q0 + ql) * EDIM + h * 64;
#pragma unroll
                for (int dn = 0; dn < 4; ++dn)
                    AO[rowoff + dn * 16 + cl] =
                        (f16)((O[qt][dn][rg] + Ox[ql * 64 + dn * 16 + cl]) * inv);
            }
    }
}

// ---------------------------------------------------------------------------
extern "C" void kernel_launch(void* const* d_in, const int* in_sizes, int n_in,
                              void* d_out, int out_size, void* d_ws, size_t ws_size,
                              hipStream_t stream)
{
    const float* x  = (const float*)d_in[0];
    const float* Wq = (const float*)d_in[1];
    const float* bq = (const float*)d_in[2];
    const float* Wk = (const float*)d_in[3];
    const float* bk = (const float*)d_in[4];
    const float* Wv = (const float*)d_in[5];
    const float* bv = (const float*)d_in[6];
    const float* Wo = (const float*)d_in[7];
    const float* bo = (const float*)d_in[8];

    char* p = (char*)d_ws;
    f16* xb  = (f16*)p;                 p += (size_t)NROW * EDIM * 2;   // 8 MB
    f16* Wqt = (f16*)p;                 p += (size_t)EDIM * EDIM * 2;   // 2 MB
    f16* Wkt = (f16*)p;                 p += (size_t)EDIM * EDIM * 2;
    f16* Wvt = (f16*)p;                 p += (size_t)EDIM * EDIM * 2;
    f16* Wot = (f16*)p;                 p += (size_t)EDIM * EDIM * 2;
    f16* Qhb = (f16*)p;                 p += (size_t)NROW * EDIM * 2;   // [b,h,s,d]
    f16* Khb = (f16*)p;                 p += (size_t)NROW * EDIM * 2;
    f16* Vtb = (f16*)p;                 p += (size_t)NROW * EDIM * 2;   // [b,h,d,s]
    f16* AOb = (f16*)p;                 p += (size_t)NROW * EDIM * 2;   // [b,s,e]

    cast_f16_kernel<<<NROW * EDIM / 1024, 256, 0, stream>>>(x, xb);
    transcast_kernel<<<dim3(32, 32), 256, 0, stream>>>(Wq, Wqt);
    transcast_kernel<<<dim3(32, 32), 256, 0, stream>>>(Wk, Wkt);
    transcast_kernel<<<dim3(32, 32), 256, 0, stream>>>(Wv, Wvt);
    transcast_kernel<<<dim3(32, 32), 256, 0, stream>>>(Wo, Wot);

    // fused Q/K/V projections: 768 blocks = 3 blocks/CU
    gemm_f16<<<dim3(NROW / 128, EDIM / 128, 3), 256, 0, stream>>>(
        xb, Wqt, Wkt, Wvt, bq, bk, bv, Qhb, Khb, Vtb, 1, 1, 2);

    yat_attn<<<dim3(SEQ / 128, BATCH * NH), 256, 0, stream>>>(Qhb, Khb, Vtb, AOb);

    gemm_f16<<<dim3(NROW / 128, EDIM / 128, 1), 256, 0, stream>>>(
        AOb, Wot, Wot, Wot, bo, bo, bo, d_out, d_out, d_out, 0, 0, 0);
}